// Round 11
// baseline (96.408 us; speedup 1.0000x reference)
//
#include <hip/hip_runtime.h>
#include <hip/hip_bf16.h>
#include <math.h>

#define DFEAT 128
#define KNBR  16
#define NPB   32    // nodes per block
#define NTHR  128   // threads per block (2 waves)

typedef __attribute__((ext_vector_type(8))) short short8;
typedef __attribute__((ext_vector_type(4))) float f32x4;
typedef __attribute__((ext_vector_type(2))) unsigned u32x2;
typedef __attribute__((ext_vector_type(4))) unsigned u32x4;

__device__ __forceinline__ unsigned short f2bf(float x) {
    union { float f; unsigned u; } v; v.f = x;
    unsigned r = v.u + 0x7FFFu + ((v.u >> 16) & 1u);   // round-nearest-even
    return (unsigned short)(r >> 16);
}
__device__ __forceinline__ float bf2f(unsigned short u) {
    union { unsigned u; float f; } v; v.u = ((unsigned)u) << 16; return v.f;
}
__device__ __forceinline__ bool detect_idx64(const int* p) {
    return ((p[1] | p[3] | p[5] | p[7] | p[9] | p[11] | p[13] | p[15]) == 0);
}

// ---- fused prep: wcat (first 4096 threads) + h16 / int8-row-scaled h8i (rest) ----
__global__ __launch_bounds__(256)
void prep_kernel(const float* __restrict__ h,
                 const float* __restrict__ wself,
                 const float* __restrict__ wnei,
                 unsigned short* __restrict__ h16,
                 unsigned short* __restrict__ wcat,
                 unsigned char* __restrict__ h8i,
                 float* __restrict__ sc,
                 int ntot8) {
    const int t = blockIdx.x * 256 + threadIdx.x;
    if (t < 4096) {
        const int base = t * 8;
        const int j = base >> 8;
        const int d0 = base & 255;
        const float* src = (d0 < DFEAT) ? (wself + j * DFEAT + d0)
                                        : (wnei  + j * DFEAT + (d0 - DFEAT));
        f32x4 a = ((const f32x4*)src)[0], b = ((const f32x4*)src)[1];
        short8 o;
        o[0] = f2bf(a[0]); o[1] = f2bf(a[1]); o[2] = f2bf(a[2]); o[3] = f2bf(a[3]);
        o[4] = f2bf(b[0]); o[5] = f2bf(b[1]); o[6] = f2bf(b[2]); o[7] = f2bf(b[3]);
        *(short8*)(wcat + base) = o;
        return;
    }
    const long u = (long)t - 4096;
    if (u >= ntot8) return;
    f32x4 a = __builtin_nontemporal_load((const f32x4*)(h + u * 8));
    f32x4 b = __builtin_nontemporal_load((const f32x4*)(h + u * 8) + 1);
    short8 o;
    o[0] = f2bf(a[0]); o[1] = f2bf(a[1]); o[2] = f2bf(a[2]); o[3] = f2bf(a[3]);
    o[4] = f2bf(b[0]); o[5] = f2bf(b[1]); o[6] = f2bf(b[2]); o[7] = f2bf(b[3]);
    __builtin_nontemporal_store(o, (short8*)(h16 + u * 8));

    if (h8i) {
        float m = 0.f;
        #pragma unroll
        for (int d = 0; d < 4; ++d) { m = fmaxf(m, fabsf(a[d])); m = fmaxf(m, fabsf(b[d])); }
        #pragma unroll
        for (int mk = 1; mk < 16; mk <<= 1) m = fmaxf(m, __shfl_xor(m, mk, 64));
        const float inv = (m > 0.f) ? 127.f / m : 0.f;
        u32x2 q;
        q[0] = ((unsigned)((int)rintf(a[0] * inv) & 255))
             | ((unsigned)((int)rintf(a[1] * inv) & 255) << 8)
             | ((unsigned)((int)rintf(a[2] * inv) & 255) << 16)
             | ((unsigned)((int)rintf(a[3] * inv) & 255) << 24);
        q[1] = ((unsigned)((int)rintf(b[0] * inv) & 255))
             | ((unsigned)((int)rintf(b[1] * inv) & 255) << 8)
             | ((unsigned)((int)rintf(b[2] * inv) & 255) << 16)
             | ((unsigned)((int)rintf(b[3] * inv) & 255) << 24);
        __builtin_nontemporal_store(q, (u32x2*)(h8i + u * 8));
        if ((u & 15) == 0) sc[u >> 4] = m * (1.f / 127.f);
    }
}

// MODE: 0 = f32 direct, 1 = bf16 table, 5 = async global_load_lds int8 gather
template<int MODE>
__global__ __launch_bounds__(NTHR, 4)
void sage_fused_kernel(const float* __restrict__ h,
                       const unsigned short* __restrict__ h16,
                       const unsigned char* __restrict__ h8i,
                       const float* __restrict__ sc,
                       const int* __restrict__ nbr32,
                       const float* __restrict__ nbrw,
                       const unsigned short* __restrict__ wcat,
                       const float* __restrict__ gamma,
                       const float* __restrict__ beta,
                       float* __restrict__ out,
                       int N) {
    // x tile: 32 nodes x 256 k, bf16, XOR-swizzled on 16B chunks (c ^= row&7)
    __shared__ __align__(16) unsigned short xlds[NPB][256];      // 16 KB
    __shared__ __align__(16) unsigned char  ring[2][2][4096];    // 16 KB: [wave][slot][pair]
    __shared__ unsigned idx_lds[NPB][KNBR];                      // 2 KB
    __shared__ float    w_lds[NPB][KNBR];                        // 2 KB

    const int tid = threadIdx.x;
    const int nb  = blockIdx.x * NPB;
    const int l   = tid & 63;
    const int wvi = tid >> 6;     // wave 0..1

    // ---------------- Phase 1: gather + stage ----------------
    if constexpr (MODE == 5) {
        const bool idx64 = detect_idx64(nbr32);
        // ---- Phase A: stage self rows + edge metadata (all compiler loads drain at barrier)
        {
            const int i  = tid >> 2;          // node 0..31
            const int qq = tid & 3;           // chunk quad
            int n = nb + i; if (n >= N) n = N - 1;
            #pragma unroll
            for (int m = 0; m < 4; ++m) {
                const int c4 = qq * 4 + m;
                short8 v = *(const short8*)(h16 + (long)n * DFEAT + c4 * 8);
                *(short8*)&xlds[i][(c4 ^ (i & 7)) * 8] = v;
            }
            #pragma unroll
            for (int j = 0; j < 4; ++j) {
                const int e = tid * 4 + j;    // 0..511
                const int ii = e >> 4, k = e & 15;
                int nn = nb + ii; if (nn >= N) nn = N - 1;
                const int ee = nn * KNBR + k;
                const int id = nbr32[idx64 ? 2 * ee : ee];
                idx_lds[ii][k] = (unsigned)id;
                w_lds[ii][k]   = nbrw[ee] * sc[id];
            }
        }
        __syncthreads();   // drains all compiler vmem; gather loop below is pure asm-counted

        unsigned char* rb0 = &ring[wvi][0][0];
        unsigned char* rb1 = &ring[wvi][1][0];

        // issue one pair (2 nodes) = 4 x global_load_lds (1KB each, rows row-major)
        #define GLD(IA, ROFS, RB, LOFS)  do {                                         \
            unsigned _id = idx_lds[(IA)][(l >> 3) + (ROFS)];                          \
            const unsigned char* _g = h8i + (size_t)_id * DFEAT + (l & 7) * 16;       \
            __builtin_amdgcn_global_load_lds(                                         \
                (const __attribute__((address_space(1))) void*)_g,                    \
                (__attribute__((address_space(3))) void*)((RB) + (LOFS)), 16, 0, 0);  \
        } while (0)
        #define ISSUE_PAIR(P2, RB) do {                                               \
            const int _ia = wvi * 16 + 2 * (P2);                                      \
            GLD(_ia, 0, RB, 0); GLD(_ia, 8, RB, 1024);                                \
            GLD(_ia + 1, 0, RB, 2048); GLD(_ia + 1, 8, RB, 3072);                     \
        } while (0)

        ISSUE_PAIR(0, rb0);
        ISSUE_PAIR(1, rb1);

        const int hh = l >> 5;          // node half within pair
        const int j  = l & 31;          // dims 4j..4j+3
        #pragma unroll
        for (int p = 0; p < 8; ++p) {
            if (p < 7) { asm volatile("s_waitcnt vmcnt(4)" ::: "memory"); }
            else       { asm volatile("s_waitcnt vmcnt(0)" ::: "memory"); }
            __builtin_amdgcn_sched_barrier(0);

            const int inode = wvi * 16 + 2 * p + hh;
            const unsigned char* nbase = ((p & 1) ? rb1 : rb0) + hh * 2048;
            f32x4 acc = {0.f, 0.f, 0.f, 0.f};
            #pragma unroll
            for (int r = 0; r < 16; ++r) {
                const float wk = w_lds[inode][r];
                const unsigned u = *(const unsigned*)(nbase + r * 128 + j * 4);
                acc[0] += wk * (float)(signed char)(u & 0xFF);
                acc[1] += wk * (float)(signed char)((u >> 8) & 0xFF);
                acc[2] += wk * (float)(signed char)((u >> 16) & 0xFF);
                acc[3] += wk * (float)(signed char)(u >> 24);
            }
            {   // store agg dims 4j..4j+3 as bf16 into swizzled xlds
                ushort4 o;
                o.x = f2bf(acc[0]); o.y = f2bf(acc[1]);
                o.z = f2bf(acc[2]); o.w = f2bf(acc[3]);
                const int c4 = 16 + (j >> 1);
                const int cs = c4 ^ (inode & 7);
                *(ushort4*)((char*)&xlds[0][0] + inode * 512 + cs * 16 + 8 * (j & 1)) = o;
            }
            if (p + 2 < 8) { if (p & 1) ISSUE_PAIR(p + 2, rb1); else ISSUE_PAIR(p + 2, rb0); }
            __builtin_amdgcn_sched_barrier(0);
        }
        #undef GLD
        #undef ISSUE_PAIR
    } else if constexpr (MODE == 1) {
        const bool idx64 = detect_idx64(nbr32);
        const int q  = l & 15;
        const int gb = l & 48;
        const int i0 = wvi * 16 + (l >> 4) * 4;
        #pragma unroll 1
        for (int r = 0; r < 4; ++r) {
            const int i = i0 + r;
            int n = nb + i; if (n >= N) n = N - 1;
            const int e0 = n * KNBR + q;
            int myidx = nbr32[idx64 ? 2 * e0 : e0];
            float myw = nbrw[e0];
            short8 hv = *(const short8*)(h16 + (long)n * DFEAT + q * 8);
            float acc[8] = {0.f,0.f,0.f,0.f,0.f,0.f,0.f,0.f};
            #pragma unroll
            for (int k = 0; k < KNBR; ++k) {
                int ik = __shfl(myidx, gb + k, 64);
                short8 nv = *(const short8*)(h16 + (long)ik * DFEAT + q * 8);
                float wk = __shfl(myw, gb + k, 64);
                #pragma unroll
                for (int d = 0; d < 8; ++d)
                    acc[d] += wk * bf2f((unsigned short)nv[d]);
            }
            *(short8*)&xlds[i][(q ^ (i & 7)) * 8] = hv;
            short8 ab;
            #pragma unroll
            for (int d = 0; d < 8; ++d) ab[d] = f2bf(acc[d]);
            *(short8*)&xlds[i][((16 + q) ^ (i & 7)) * 8] = ab;
        }
    } else {
        const bool idx64 = detect_idx64(nbr32);
        const int q  = l & 15;
        const int i0 = wvi * 16 + (l >> 4) * 4;
        #pragma unroll 1
        for (int r = 0; r < 4; ++r) {
            const int i = i0 + r;
            int n = nb + i; if (n >= N) n = N - 1;
            short8 hv;
            float acc[8] = {0.f,0.f,0.f,0.f,0.f,0.f,0.f,0.f};
            const f32x4* hrow = (const f32x4*)(h + (long)n * DFEAT + q * 8);
            f32x4 h0 = hrow[0], h1 = hrow[1];
            hv[0] = f2bf(h0[0]); hv[1] = f2bf(h0[1]); hv[2] = f2bf(h0[2]); hv[3] = f2bf(h0[3]);
            hv[4] = f2bf(h1[0]); hv[5] = f2bf(h1[1]); hv[6] = f2bf(h1[2]); hv[7] = f2bf(h1[3]);
            const int e0 = n * KNBR;
            #pragma unroll 4
            for (int k = 0; k < KNBR; ++k) {
                float w = nbrw[e0 + k];
                int idx = nbr32[idx64 ? 2 * (e0 + k) : (e0 + k)];
                const f32x4* nrow = (const f32x4*)(h + (long)idx * DFEAT + q * 8);
                f32x4 n0 = nrow[0], n1 = nrow[1];
                acc[0] += w * n0[0]; acc[1] += w * n0[1];
                acc[2] += w * n0[2]; acc[3] += w * n0[3];
                acc[4] += w * n1[0]; acc[5] += w * n1[1];
                acc[6] += w * n1[2]; acc[7] += w * n1[3];
            }
            *(short8*)&xlds[i][(q ^ (i & 7)) * 8] = hv;
            short8 ab;
            #pragma unroll
            for (int d = 0; d < 8; ++d) ab[d] = f2bf(acc[d]);
            *(short8*)&xlds[i][((16 + q) ^ (i & 7)) * 8] = ab;
        }
    }
    __syncthreads();

    // ---------------- Phase 2: MFMA GEMM (32 nodes x 128 j, K=256) ----------------
    const int wv  = wvi;
    const int col = l & 15;
    const int kg  = l >> 4;       // 0..3

    f32x4 acc2[2][4];
    #pragma unroll
    for (int s = 0; s < 2; ++s)
        #pragma unroll
        for (int t = 0; t < 4; ++t)
            acc2[s][t] = (f32x4){0.f, 0.f, 0.f, 0.f};

    const unsigned short* wb0 = wcat + (wv * 64 + col) * 256 + kg * 8;

    #pragma unroll
    for (int kk = 0; kk < 8; ++kk) {
        short8 bt0 = *(const short8*)(wb0 + kk * 32);
        short8 bt1 = *(const short8*)(wb0 + 16 * 256 + kk * 32);
        short8 bt2 = *(const short8*)(wb0 + 32 * 256 + kk * 32);
        short8 bt3 = *(const short8*)(wb0 + 48 * 256 + kk * 32);
        #pragma unroll
        for (int s = 0; s < 2; ++s) {
            const int row = s * 16 + col;
            const int c = (kk * 4 + kg) ^ (row & 7);
            short8 a = *(const short8*)&xlds[row][c * 8];
            acc2[s][0] = __builtin_amdgcn_mfma_f32_16x16x32_bf16(a, bt0, acc2[s][0], 0, 0, 0);
            acc2[s][1] = __builtin_amdgcn_mfma_f32_16x16x32_bf16(a, bt1, acc2[s][1], 0, 0, 0);
            acc2[s][2] = __builtin_amdgcn_mfma_f32_16x16x32_bf16(a, bt2, acc2[s][2], 0, 0, 0);
            acc2[s][3] = __builtin_amdgcn_mfma_f32_16x16x32_bf16(a, bt3, acc2[s][3], 0, 0, 0);
        }
    }

    // ---------------- Phase 3: GELU (exact erf) ----------------
    float y[2][4][4];
    #pragma unroll
    for (int s = 0; s < 2; ++s)
        #pragma unroll
        for (int t = 0; t < 4; ++t)
            #pragma unroll
            for (int r = 0; r < 4; ++r) {
                float x = acc2[s][t][r];
                y[s][t][r] = 0.5f * x * (1.0f + erff(x * 0.70710678118654752f));
            }

    __syncthreads();   // all xlds reads done before LN-scratch overlay writes

    // overlay LN scratch on the dead x tile
    float* lsum = (float*)&xlds[0][0];        // [2][32]
    float* lsq  = lsum + 2 * NPB;             // [2][32]

    // ---------------- Phase 4: LN stats ----------------
    #pragma unroll
    for (int s = 0; s < 2; ++s) {
        f32x4 sm, sq;
        #pragma unroll
        for (int r = 0; r < 4; ++r) {
            float a0 = y[s][0][r], a1 = y[s][1][r], a2 = y[s][2][r], a3 = y[s][3][r];
            sm[r] = (a0 + a1) + (a2 + a3);
            sq[r] = (a0 * a0 + a1 * a1) + (a2 * a2 + a3 * a3);
        }
        #pragma unroll
        for (int m = 1; m < 16; m <<= 1) {
            #pragma unroll
            for (int r = 0; r < 4; ++r) {
                sm[r] += __shfl_xor(sm[r], m, 64);
                sq[r] += __shfl_xor(sq[r], m, 64);
            }
        }
        if (col == 0) {
            *(f32x4*)&lsum[wv * NPB + s * 16 + kg * 4] = sm;
            *(f32x4*)&lsq [wv * NPB + s * 16 + kg * 4] = sq;
        }
    }
    __syncthreads();

    // ---------------- Phase 5: LN apply + store (non-temporal) ----------------
    float g[4], be[4];
    #pragma unroll
    for (int t = 0; t < 4; ++t) {
        g[t]  = gamma[wv * 64 + t * 16 + col];
        be[t] = beta [wv * 64 + t * 16 + col];
    }

    #pragma unroll
    for (int s = 0; s < 2; ++s) {
        f32x4 sm, sq;
        {
            f32x4 a0 = *(const f32x4*)&lsum[0 * NPB + s * 16 + kg * 4];
            f32x4 a1 = *(const f32x4*)&lsum[1 * NPB + s * 16 + kg * 4];
            f32x4 b0 = *(const f32x4*)&lsq [0 * NPB + s * 16 + kg * 4];
            f32x4 b1 = *(const f32x4*)&lsq [1 * NPB + s * 16 + kg * 4];
            sm = a0 + a1; sq = b0 + b1;
        }
        #pragma unroll
        for (int r = 0; r < 4; ++r) {
            const int i = s * 16 + kg * 4 + r;
            const int n = nb + i;
            if (n < N) {
                float mean = sm[r] * (1.0f / 128.0f);
                float var  = sq[r] * (1.0f / 128.0f) - mean * mean;
                float rstd = rsqrtf(var + 1e-5f);
                long o = (long)n * DFEAT + wv * 64 + col;
                #pragma unroll
                for (int t = 0; t < 4; ++t)
                    __builtin_nontemporal_store((y[s][t][r] - mean) * rstd * g[t] + be[t],
                                                &out[o + t * 16]);
            }
        }
    }
}

extern "C" void kernel_launch(void* const* d_in, const int* in_sizes, int n_in,
                              void* d_out, int out_size, void* d_ws, size_t ws_size,
                              hipStream_t stream) {
    const float* h     = (const float*)d_in[0];
    const int*   nbr   = (const int*)  d_in[1];
    const float* nbrw  = (const float*)d_in[2];
    const float* wself = (const float*)d_in[3];
    const float* wnei  = (const float*)d_in[4];
    const float* gamma = (const float*)d_in[5];
    const float* beta  = (const float*)d_in[6];
    const int N = in_sizes[0] / DFEAT;

    // layout: wcat 64K | h16 N*256B | sc N*4B | h8i N*128B
    unsigned short* wcat = (unsigned short*)d_ws;
    unsigned short* h16  = (unsigned short*)((char*)d_ws + 65536);
    float*          sc   = (float*)((char*)d_ws + 65536 + (size_t)N * DFEAT * 2);
    unsigned char*  h8i  = (unsigned char*)((char*)sc + (size_t)N * 4);
    const size_t need16 = 65536 + (size_t)N * DFEAT * 2;
    const size_t need3  = need16 + (size_t)N * 4 + (size_t)N * DFEAT;

    const int blocks = (N + NPB - 1) / NPB;
    const int ntot8 = N * DFEAT / 8;
    const int pthreads = 4096 + ntot8;

    if (ws_size >= need3) {
        prep_kernel<<<(pthreads + 255) / 256, 256, 0, stream>>>(h, wself, wnei, h16, wcat, h8i, sc, ntot8);
        sage_fused_kernel<5><<<blocks, NTHR, 0, stream>>>(h, h16, h8i, sc, nbr, nbrw, wcat,
                                                          gamma, beta, (float*)d_out, N);
    } else if (ws_size >= need16) {
        prep_kernel<<<(pthreads + 255) / 256, 256, 0, stream>>>(h, wself, wnei, h16, wcat,
                                                                (unsigned char*)nullptr, (float*)nullptr, ntot8);
        sage_fused_kernel<1><<<blocks, NTHR, 0, stream>>>(h, h16, (const unsigned char*)nullptr,
                                                          (const float*)nullptr, nbr, nbrw, wcat,
                                                          gamma, beta, (float*)d_out, N);
    } else {
        prep_kernel<<<(4096 + 255) / 256, 256, 0, stream>>>(h, wself, wnei, h16, wcat,
                                                            (unsigned char*)nullptr, (float*)nullptr, 0);
        sage_fused_kernel<0><<<blocks, NTHR, 0, stream>>>(h, (const unsigned short*)nullptr,
                                                          (const unsigned char*)nullptr,
                                                          (const float*)nullptr, nbr, nbrw, wcat,
                                                          gamma, beta, (float*)d_out, N);
    }
}

// Round 12
// 91.635 us; speedup vs baseline: 1.0521x; 1.0521x over previous
//
#include <hip/hip_runtime.h>
#include <hip/hip_bf16.h>
#include <math.h>

#define DFEAT 128
#define KNBR  16
#define NPB   64    // nodes per block
#define NTHR  256   // threads per block (4 waves)

typedef __attribute__((ext_vector_type(8))) short short8;
typedef __attribute__((ext_vector_type(4))) float f32x4;
typedef __attribute__((ext_vector_type(2))) unsigned u32x2;
typedef __attribute__((ext_vector_type(4))) unsigned u32x4;

__device__ __forceinline__ unsigned short f2bf(float x) {
    union { float f; unsigned u; } v; v.f = x;
    unsigned r = v.u + 0x7FFFu + ((v.u >> 16) & 1u);   // round-nearest-even
    return (unsigned short)(r >> 16);
}
__device__ __forceinline__ float bf2f(unsigned short u) {
    union { unsigned u; float f; } v; v.u = ((unsigned)u) << 16; return v.f;
}
__device__ __forceinline__ float u2f(unsigned u) {
    union { unsigned u; float f; } v; v.u = u; return v.f;
}
__device__ __forceinline__ unsigned f2u(float f) {
    union { float f; unsigned u; } v; v.f = f; return v.u;
}
__device__ __forceinline__ bool detect_idx64(const int* p) {
    return ((p[1] | p[3] | p[5] | p[7] | p[9] | p[11] | p[13] | p[15]) == 0);
}

// ---- prep 1: wcat (first 4096 threads) + h16 / int8-row-scaled h8i + sc (rest) ----
__global__ __launch_bounds__(256)
void prep_kernel(const float* __restrict__ h,
                 const float* __restrict__ wself,
                 const float* __restrict__ wnei,
                 unsigned short* __restrict__ h16,
                 unsigned short* __restrict__ wcat,
                 unsigned char* __restrict__ h8i,
                 float* __restrict__ sc,
                 int ntot8) {
    const int t = blockIdx.x * 256 + threadIdx.x;
    if (t < 4096) {
        const int base = t * 8;
        const int j = base >> 8;
        const int d0 = base & 255;
        const float* src = (d0 < DFEAT) ? (wself + j * DFEAT + d0)
                                        : (wnei  + j * DFEAT + (d0 - DFEAT));
        f32x4 a = ((const f32x4*)src)[0], b = ((const f32x4*)src)[1];
        short8 o;
        o[0] = f2bf(a[0]); o[1] = f2bf(a[1]); o[2] = f2bf(a[2]); o[3] = f2bf(a[3]);
        o[4] = f2bf(b[0]); o[5] = f2bf(b[1]); o[6] = f2bf(b[2]); o[7] = f2bf(b[3]);
        *(short8*)(wcat + base) = o;
        return;
    }
    const long u = (long)t - 4096;
    if (u >= ntot8) return;
    f32x4 a = __builtin_nontemporal_load((const f32x4*)(h + u * 8));
    f32x4 b = __builtin_nontemporal_load((const f32x4*)(h + u * 8) + 1);
    short8 o;
    o[0] = f2bf(a[0]); o[1] = f2bf(a[1]); o[2] = f2bf(a[2]); o[3] = f2bf(a[3]);
    o[4] = f2bf(b[0]); o[5] = f2bf(b[1]); o[6] = f2bf(b[2]); o[7] = f2bf(b[3]);
    __builtin_nontemporal_store(o, (short8*)(h16 + u * 8));

    if (h8i) {
        // per-row max over the 16-thread subgroup (u contiguous, 16-aligned per wave)
        float m = 0.f;
        #pragma unroll
        for (int d = 0; d < 4; ++d) { m = fmaxf(m, fabsf(a[d])); m = fmaxf(m, fabsf(b[d])); }
        #pragma unroll
        for (int mk = 1; mk < 16; mk <<= 1) m = fmaxf(m, __shfl_xor(m, mk, 64));
        const float inv = (m > 0.f) ? 127.f / m : 0.f;
        u32x2 q;
        q[0] = ((unsigned)((int)rintf(a[0] * inv) & 255))
             | ((unsigned)((int)rintf(a[1] * inv) & 255) << 8)
             | ((unsigned)((int)rintf(a[2] * inv) & 255) << 16)
             | ((unsigned)((int)rintf(a[3] * inv) & 255) << 24);
        q[1] = ((unsigned)((int)rintf(b[0] * inv) & 255))
             | ((unsigned)((int)rintf(b[1] * inv) & 255) << 8)
             | ((unsigned)((int)rintf(b[2] * inv) & 255) << 16)
             | ((unsigned)((int)rintf(b[3] * inv) & 255) << 24);
        __builtin_nontemporal_store(q, (u32x2*)(h8i + u * 8));
        if ((u & 15) == 0) sc[u >> 4] = m * (1.f / 127.f);
    }
}

// ---- prep 2: packed edge table (int32 idx, f32 w*sc[idx]) ----
// layout per node: 32 u32; lane q8 reads u32x4 at n*32+q8*4 = {id_a, w_a, id_b, w_b}
// where edge a = q8, edge b = q8+8
__global__ __launch_bounds__(256)
void prep_edges_kernel(const int* __restrict__ nbr32,
                       const float* __restrict__ nbrw,
                       const float* __restrict__ sc,
                       unsigned* __restrict__ edges,
                       int nedge) {
    const int e = blockIdx.x * 256 + threadIdx.x;
    if (e >= nedge) return;
    const bool idx64 = detect_idx64(nbr32);
    const int id = nbr32[idx64 ? 2 * e : e];
    const float w = nbrw[e] * sc[id];
    const int n = e >> 4, k = e & 15;
    const int base = n * 32 + (k & 7) * 4 + (k >> 3) * 2;
    edges[base]     = (unsigned)id;
    edges[base + 1] = f2u(w);
}

// MODE: 0 = f32 direct, 1 = bf16 table, 3 = int8 + packed-edge fused gather
template<int MODE>
__global__ __launch_bounds__(NTHR, 4)
void sage_fused_kernel(const float* __restrict__ h,
                       const unsigned short* __restrict__ h16,
                       const unsigned char* __restrict__ h8i,
                       const unsigned* __restrict__ edges,
                       const int* __restrict__ nbr32,
                       const float* __restrict__ nbrw,
                       const unsigned short* __restrict__ wcat,
                       const float* __restrict__ gamma,
                       const float* __restrict__ beta,
                       float* __restrict__ out,
                       int N) {
    // x tile: 64 nodes x 256 k, bf16, XOR-swizzled on 16B chunks (c ^= row&7)
    // LN scratch OVERLAID on xlds (dead after the MFMA loop) -> 32 KB total
    __shared__ __align__(16) unsigned short xlds[NPB][256];   // 32 KB exactly

    const int tid = threadIdx.x;
    const int nb  = blockIdx.x * NPB;
    const int l   = tid & 63;
    const int wvi = tid >> 6;     // wave 0..3

    // ---------------- Phase 1: gather + stage ----------------
    if constexpr (MODE == 3) {
        const int q8  = l & 7;          // lane-in-group: dims [q8*16, q8*16+16)
        const int gb2 = l & 56;         // 8-lane group base within wave
        const int i0b = wvi * 16 + (l >> 3) * 2;   // group's first node-in-tile
        #pragma unroll
        for (int r = 0; r < 2; ++r) {
            const int i = i0b + r;
            int n = nb + i; if (n >= N) n = N - 1;

            // one 16B load: both of this lane's edges, scale pre-folded
            u32x4 m = *(const u32x4*)(edges + (size_t)n * 32 + q8 * 4);
            const int   id0 = (int)m[0];
            const float w0  = u2f(m[1]);
            const int   id1 = (int)m[2];
            const float w1  = u2f(m[3]);

            short8 hv0 = *(const short8*)(h16 + (long)n * DFEAT + q8 * 16);
            short8 hv1 = *(const short8*)(h16 + (long)n * DFEAT + q8 * 16 + 8);
            *(short8*)&xlds[i][((2 * q8)     ^ (i & 7)) * 8] = hv0;
            *(short8*)&xlds[i][((2 * q8 + 1) ^ (i & 7)) * 8] = hv1;

            float acc[16];
            #pragma unroll
            for (int d = 0; d < 16; ++d) acc[d] = 0.f;

            #pragma unroll
            for (int k = 0; k < 16; ++k) {
                const int   ik = __shfl(k < 8 ? id0 : id1, gb2 + (k & 7), 64);
                const float wk = __shfl(k < 8 ? w0  : w1,  gb2 + (k & 7), 64);
                u32x4 nv = *(const u32x4*)(h8i + (long)ik * DFEAT + q8 * 16);
                #pragma unroll
                for (int b = 0; b < 4; ++b) {
                    const unsigned u = nv[b];
                    acc[b * 4 + 0] += wk * (float)(signed char)(u & 0xFF);
                    acc[b * 4 + 1] += wk * (float)(signed char)((u >> 8) & 0xFF);
                    acc[b * 4 + 2] += wk * (float)(signed char)((u >> 16) & 0xFF);
                    acc[b * 4 + 3] += wk * (float)(signed char)(u >> 24);
                }
            }

            short8 ab0, ab1;
            #pragma unroll
            for (int d = 0; d < 8; ++d) { ab0[d] = f2bf(acc[d]); ab1[d] = f2bf(acc[8 + d]); }
            *(short8*)&xlds[i][((16 + 2 * q8)     ^ (i & 7)) * 8] = ab0;
            *(short8*)&xlds[i][((16 + 2 * q8 + 1) ^ (i & 7)) * 8] = ab1;
        }
    } else if constexpr (MODE == 1) {
        const bool idx64 = detect_idx64(nbr32);
        const int q  = l & 15;
        const int gb = l & 48;
        const int i0 = wvi * 16 + (l >> 4) * 4;
        #pragma unroll 1
        for (int r = 0; r < 4; ++r) {
            const int i = i0 + r;
            int n = nb + i; if (n >= N) n = N - 1;
            const int e0 = n * KNBR + q;
            int myidx = nbr32[idx64 ? 2 * e0 : e0];
            float myw = nbrw[e0];
            short8 hv = *(const short8*)(h16 + (long)n * DFEAT + q * 8);
            float acc[8] = {0.f,0.f,0.f,0.f,0.f,0.f,0.f,0.f};
            #pragma unroll
            for (int k = 0; k < KNBR; ++k) {
                int ik = __shfl(myidx, gb + k, 64);
                short8 nv = *(const short8*)(h16 + (long)ik * DFEAT + q * 8);
                float wk = __shfl(myw, gb + k, 64);
                #pragma unroll
                for (int d = 0; d < 8; ++d)
                    acc[d] += wk * bf2f((unsigned short)nv[d]);
            }
            *(short8*)&xlds[i][(q ^ (i & 7)) * 8] = hv;
            short8 ab;
            #pragma unroll
            for (int d = 0; d < 8; ++d) ab[d] = f2bf(acc[d]);
            *(short8*)&xlds[i][((16 + q) ^ (i & 7)) * 8] = ab;
        }
    } else {
        const bool idx64 = detect_idx64(nbr32);
        const int q  = l & 15;
        const int i0 = wvi * 16 + (l >> 4) * 4;
        #pragma unroll 1
        for (int r = 0; r < 4; ++r) {
            const int i = i0 + r;
            int n = nb + i; if (n >= N) n = N - 1;
            short8 hv;
            float acc[8] = {0.f,0.f,0.f,0.f,0.f,0.f,0.f,0.f};
            const f32x4* hrow = (const f32x4*)(h + (long)n * DFEAT + q * 8);
            f32x4 h0 = hrow[0], h1 = hrow[1];
            hv[0] = f2bf(h0[0]); hv[1] = f2bf(h0[1]); hv[2] = f2bf(h0[2]); hv[3] = f2bf(h0[3]);
            hv[4] = f2bf(h1[0]); hv[5] = f2bf(h1[1]); hv[6] = f2bf(h1[2]); hv[7] = f2bf(h1[3]);
            const int e0 = n * KNBR;
            #pragma unroll 4
            for (int k = 0; k < KNBR; ++k) {
                float w = nbrw[e0 + k];
                int idx = nbr32[idx64 ? 2 * (e0 + k) : (e0 + k)];
                const f32x4* nrow = (const f32x4*)(h + (long)idx * DFEAT + q * 8);
                f32x4 n0 = nrow[0], n1 = nrow[1];
                acc[0] += w * n0[0]; acc[1] += w * n0[1];
                acc[2] += w * n0[2]; acc[3] += w * n0[3];
                acc[4] += w * n1[0]; acc[5] += w * n1[1];
                acc[6] += w * n1[2]; acc[7] += w * n1[3];
            }
            *(short8*)&xlds[i][(q ^ (i & 7)) * 8] = hv;
            short8 ab;
            #pragma unroll
            for (int d = 0; d < 8; ++d) ab[d] = f2bf(acc[d]);
            *(short8*)&xlds[i][((16 + q) ^ (i & 7)) * 8] = ab;
        }
    }
    __syncthreads();

    // ---------------- Phase 2: MFMA GEMM (64 nodes x 128 j, K=256) ----------------
    const int wv  = wvi;          // wave owns j in [wv*32, wv*32+32)
    const int col = l & 15;
    const int kg  = l >> 4;       // 0..3

    f32x4 acc2[4][2];
    #pragma unroll
    for (int s = 0; s < 4; ++s)
        #pragma unroll
        for (int t = 0; t < 2; ++t)
            acc2[s][t] = (f32x4){0.f, 0.f, 0.f, 0.f};

    const unsigned short* wbase0 = wcat + (wv * 32 + col) * 256 + kg * 8;
    const unsigned short* wbase1 = wbase0 + 16 * 256;

    #pragma unroll
    for (int kk = 0; kk < 8; ++kk) {
        short8 b0 = *(const short8*)(wbase0 + kk * 32);   // B[k][col] = Wcat[j][k]
        short8 b1 = *(const short8*)(wbase1 + kk * 32);
        #pragma unroll
        for (int s = 0; s < 4; ++s) {
            const int row = s * 16 + col;                  // A row = node in tile
            const int c = (kk * 4 + kg) ^ (row & 7);       // swizzled 16B chunk
            short8 a = *(const short8*)&xlds[row][c * 8];
            acc2[s][0] = __builtin_amdgcn_mfma_f32_16x16x32_bf16(a, b0, acc2[s][0], 0, 0, 0);
            acc2[s][1] = __builtin_amdgcn_mfma_f32_16x16x32_bf16(a, b1, acc2[s][1], 0, 0, 0);
        }
    }

    // ---------------- Phase 3: GELU (exact erf) ----------------
    float y[4][2][4];
    #pragma unroll
    for (int s = 0; s < 4; ++s)
        #pragma unroll
        for (int t = 0; t < 2; ++t)
            #pragma unroll
            for (int r = 0; r < 4; ++r) {
                float x = acc2[s][t][r];
                y[s][t][r] = 0.5f * x * (1.0f + erff(x * 0.70710678118654752f));
            }

    __syncthreads();   // all xlds reads done before LN-scratch overlay writes

    // overlay LN scratch on the dead x tile
    float* lsum = (float*)&xlds[0][0];        // [4][64]
    float* lsq  = lsum + 4 * NPB;             // [4][64]

    // ---------------- Phase 4: LN stats ----------------
    #pragma unroll
    for (int s = 0; s < 4; ++s) {
        f32x4 sm, sq;
        #pragma unroll
        for (int r = 0; r < 4; ++r) {
            float a0 = y[s][0][r], a1 = y[s][1][r];
            sm[r] = a0 + a1;
            sq[r] = a0 * a0 + a1 * a1;
        }
        #pragma unroll
        for (int m = 1; m < 16; m <<= 1) {
            #pragma unroll
            for (int r = 0; r < 4; ++r) {
                sm[r] += __shfl_xor(sm[r], m, 64);
                sq[r] += __shfl_xor(sq[r], m, 64);
            }
        }
        if (col == 0) {
            *(f32x4*)&lsum[wv * NPB + s * 16 + kg * 4] = sm;
            *(f32x4*)&lsq [wv * NPB + s * 16 + kg * 4] = sq;
        }
    }
    __syncthreads();

    // ---------------- Phase 5: LN apply + store (non-temporal) ----------------
    const float g0  = gamma[wv * 32 + col];
    const float g1  = gamma[wv * 32 + 16 + col];
    const float be0 = beta [wv * 32 + col];
    const float be1 = beta [wv * 32 + 16 + col];

    #pragma unroll
    for (int s = 0; s < 4; ++s) {
        f32x4 sm = {0.f,0.f,0.f,0.f}, sq = {0.f,0.f,0.f,0.f};
        #pragma unroll
        for (int u = 0; u < 4; ++u) {
            f32x4 a = *(const f32x4*)&lsum[u * NPB + s * 16 + kg * 4];
            f32x4 b = *(const f32x4*)&lsq [u * NPB + s * 16 + kg * 4];
            sm += a; sq += b;
        }
        #pragma unroll
        for (int r = 0; r < 4; ++r) {
            const int i = s * 16 + kg * 4 + r;
            const int n = nb + i;
            if (n < N) {
                float mean = sm[r] * (1.0f / 128.0f);
                float var  = sq[r] * (1.0f / 128.0f) - mean * mean;
                float rstd = rsqrtf(var + 1e-5f);
                long o = (long)n * DFEAT + wv * 32 + col;
                __builtin_nontemporal_store((y[s][0][r] - mean) * rstd * g0 + be0, &out[o]);
                __builtin_nontemporal_store((y[s][1][r] - mean) * rstd * g1 + be1, &out[o + 16]);
            }
        }
    }
}

extern "C" void kernel_launch(void* const* d_in, const int* in_sizes, int n_in,
                              void* d_out, int out_size, void* d_ws, size_t ws_size,
                              hipStream_t stream) {
    const float* h     = (const float*)d_in[0];
    const int*   nbr   = (const int*)  d_in[1];
    const float* nbrw  = (const float*)d_in[2];
    const float* wself = (const float*)d_in[3];
    const float* wnei  = (const float*)d_in[4];
    const float* gamma = (const float*)d_in[5];
    const float* beta  = (const float*)d_in[6];
    const int N = in_sizes[0] / DFEAT;

    // layout: wcat 64K | h16 N*256B | sc N*4B | h8i N*128B | edges N*128B
    unsigned short* wcat  = (unsigned short*)d_ws;
    unsigned short* h16   = (unsigned short*)((char*)d_ws + 65536);
    float*          sc    = (float*)((char*)d_ws + 65536 + (size_t)N * DFEAT * 2);
    unsigned char*  h8i   = (unsigned char*)((char*)sc + (size_t)N * 4);
    unsigned*       edges = (unsigned*)(h8i + (size_t)N * DFEAT);
    const size_t need16 = 65536 + (size_t)N * DFEAT * 2;
    const size_t need3  = need16 + (size_t)N * 4 + (size_t)N * DFEAT + (size_t)N * DFEAT;

    const int blocks = (N + NPB - 1) / NPB;
    const int ntot8 = N * DFEAT / 8;
    const int pthreads = 4096 + ntot8;
    const int nedge = N * KNBR;

    if (ws_size >= need3) {
        prep_kernel<<<(pthreads + 255) / 256, 256, 0, stream>>>(h, wself, wnei, h16, wcat, h8i, sc, ntot8);
        prep_edges_kernel<<<(nedge + 255) / 256, 256, 0, stream>>>(nbr, nbrw, sc, edges, nedge);
        sage_fused_kernel<3><<<blocks, NTHR, 0, stream>>>(h, h16, h8i, edges, nbr, nbrw, wcat,
                                                          gamma, beta, (float*)d_out, N);
    } else if (ws_size >= need16) {
        prep_kernel<<<(pthreads + 255) / 256, 256, 0, stream>>>(h, wself, wnei, h16, wcat,
                                                                (unsigned char*)nullptr, (float*)nullptr, ntot8);
        sage_fused_kernel<1><<<blocks, NTHR, 0, stream>>>(h, h16, (const unsigned char*)nullptr,
                                                          (const unsigned*)nullptr, nbr, nbrw, wcat,
                                                          gamma, beta, (float*)d_out, N);
    } else {
        prep_kernel<<<(4096 + 255) / 256, 256, 0, stream>>>(h, wself, wnei, h16, wcat,
                                                            (unsigned char*)nullptr, (float*)nullptr, 0);
        sage_fused_kernel<0><<<blocks, NTHR, 0, stream>>>(h, (const unsigned short*)nullptr,
                                                          (const unsigned char*)nullptr,
                                                          (const unsigned*)nullptr, nbr, nbrw, wcat,
                                                          gamma, beta, (float*)d_out, N);
    }
}

// Round 13
// 85.968 us; speedup vs baseline: 1.1214x; 1.0659x over previous
//
#include <hip/hip_runtime.h>
#include <hip/hip_bf16.h>
#include <math.h>

#define DFEAT 128
#define KNBR  16
#define NPB   64   // nodes per block

typedef __attribute__((ext_vector_type(8))) short short8;
typedef __attribute__((ext_vector_type(4))) float f32x4;
typedef __attribute__((ext_vector_type(2))) unsigned u32x2;
typedef __attribute__((ext_vector_type(4))) unsigned u32x4;

__device__ __forceinline__ unsigned short f2bf(float x) {
    union { float f; unsigned u; } v; v.f = x;
    unsigned r = v.u + 0x7FFFu + ((v.u >> 16) & 1u);   // round-nearest-even
    return (unsigned short)(r >> 16);
}
__device__ __forceinline__ float bf2f(unsigned short u) {
    union { unsigned u; float f; } v; v.u = ((unsigned)u) << 16; return v.f;
}

// ---- fused prep: wcat (first 4096 threads) + h16 / int8-row-scaled h8i (rest) ----
// h-thread u: row = u>>4, part = u&15, dims [part*8, part*8+8)
__global__ __launch_bounds__(256)
void prep_kernel(const float* __restrict__ h,
                 const float* __restrict__ wself,
                 const float* __restrict__ wnei,
                 unsigned short* __restrict__ h16,
                 unsigned short* __restrict__ wcat,
                 unsigned char* __restrict__ h8i,
                 float* __restrict__ sc,
                 int ntot8) {
    const int t = blockIdx.x * 256 + threadIdx.x;
    if (t < 4096) {
        const int base = t * 8;
        const int j = base >> 8;
        const int d0 = base & 255;
        const float* src = (d0 < DFEAT) ? (wself + j * DFEAT + d0)
                                        : (wnei  + j * DFEAT + (d0 - DFEAT));
        f32x4 a = ((const f32x4*)src)[0], b = ((const f32x4*)src)[1];
        short8 o;
        o[0] = f2bf(a[0]); o[1] = f2bf(a[1]); o[2] = f2bf(a[2]); o[3] = f2bf(a[3]);
        o[4] = f2bf(b[0]); o[5] = f2bf(b[1]); o[6] = f2bf(b[2]); o[7] = f2bf(b[3]);
        *(short8*)(wcat + base) = o;
        return;
    }
    const long u = (long)t - 4096;
    if (u >= ntot8) return;
    f32x4 a = __builtin_nontemporal_load((const f32x4*)(h + u * 8));
    f32x4 b = __builtin_nontemporal_load((const f32x4*)(h + u * 8) + 1);
    short8 o;
    o[0] = f2bf(a[0]); o[1] = f2bf(a[1]); o[2] = f2bf(a[2]); o[3] = f2bf(a[3]);
    o[4] = f2bf(b[0]); o[5] = f2bf(b[1]); o[6] = f2bf(b[2]); o[7] = f2bf(b[3]);
    __builtin_nontemporal_store(o, (short8*)(h16 + u * 8));

    if (h8i) {
        // per-row max over the 16-thread subgroup (u contiguous, 16-aligned per wave)
        float m = 0.f;
        #pragma unroll
        for (int d = 0; d < 4; ++d) { m = fmaxf(m, fabsf(a[d])); m = fmaxf(m, fabsf(b[d])); }
        #pragma unroll
        for (int mk = 1; mk < 16; mk <<= 1) m = fmaxf(m, __shfl_xor(m, mk, 64));
        const float inv = (m > 0.f) ? 127.f / m : 0.f;
        u32x2 q;
        q[0] = ((unsigned)((int)rintf(a[0] * inv) & 255))
             | ((unsigned)((int)rintf(a[1] * inv) & 255) << 8)
             | ((unsigned)((int)rintf(a[2] * inv) & 255) << 16)
             | ((unsigned)((int)rintf(a[3] * inv) & 255) << 24);
        q[1] = ((unsigned)((int)rintf(b[0] * inv) & 255))
             | ((unsigned)((int)rintf(b[1] * inv) & 255) << 8)
             | ((unsigned)((int)rintf(b[2] * inv) & 255) << 16)
             | ((unsigned)((int)rintf(b[3] * inv) & 255) << 24);
        __builtin_nontemporal_store(q, (u32x2*)(h8i + u * 8));
        if ((u & 15) == 0) sc[u >> 4] = m * (1.f / 127.f);
    }
}

// MODE: 0 = f32 direct, 1 = bf16 table, 3 = int8+row-scale gather, bf16 self
template<int MODE>
__global__ __launch_bounds__(256, 4)
void sage_fused_kernel(const float* __restrict__ h,
                       const unsigned short* __restrict__ h16,
                       const unsigned char* __restrict__ h8i,
                       const float* __restrict__ sc,
                       const int* __restrict__ nbr32,
                       const float* __restrict__ nbrw,
                       const unsigned short* __restrict__ wcat,
                       const float* __restrict__ gamma,
                       const float* __restrict__ beta,
                       float* __restrict__ out,
                       int N) {
    // x tile: 64 nodes x 256 k, bf16, XOR-swizzled on 16B chunks (c ^= row&7)
    // LN scratch is OVERLAID on xlds (dead after the MFMA loop) -> 32 KB total
    __shared__ __align__(16) unsigned short xlds[NPB][256];   // 32 KB exactly

    const int tid = threadIdx.x;
    const int nb  = blockIdx.x * NPB;

    // int64-vs-int32 index dtype detection (idx < 2^17 => int64 odd words all 0)
    const bool idx64 = ((nbr32[1] | nbr32[3] | nbr32[5] | nbr32[7] |
                         nbr32[9] | nbr32[11] | nbr32[13] | nbr32[15]) == 0);

    const int l   = tid & 63;
    const int wvi = tid >> 6;     // wave 0..3

    // ---------------- Phase 1: gather + stage ----------------
    if constexpr (MODE == 3) {
        const int q8  = l & 7;          // lane-in-group: dims [q8*16, q8*16+16)
        const int gb2 = l & 56;         // 8-lane group base within wave
        const int i0b = wvi * 16 + (l >> 3) * 2;   // group's first node-in-tile

        #pragma unroll
        for (int r = 0; r < 2; ++r) {
            const int i = i0b + r;
            int n = nb + i; if (n >= N) n = N - 1;

            // lane owns edges q8 and q8+8 of node n; fold row-scale into weight
            const int e0 = n * KNBR + q8;
            const int id0 = nbr32[idx64 ? 2 * e0 : e0];
            const int id1 = nbr32[idx64 ? 2 * (e0 + 8) : (e0 + 8)];
            const float w0 = nbrw[e0]     * sc[id0];
            const float w1 = nbrw[e0 + 8] * sc[id1];

            // self row (bf16 table): dims [q8*16, q8*16+16) = chunks 2q8, 2q8+1
            short8 hv0 = *(const short8*)(h16 + (long)n * DFEAT + q8 * 16);
            short8 hv1 = *(const short8*)(h16 + (long)n * DFEAT + q8 * 16 + 8);
            *(short8*)&xlds[i][((2 * q8)     ^ (i & 7)) * 8] = hv0;
            *(short8*)&xlds[i][((2 * q8 + 1) ^ (i & 7)) * 8] = hv1;

            float acc[16];
            #pragma unroll
            for (int d = 0; d < 16; ++d) acc[d] = 0.f;

            #pragma unroll
            for (int k = 0; k < 16; ++k) {
                const int   ik = __shfl(k < 8 ? id0 : id1, gb2 + (k & 7), 64);
                const float wk = __shfl(k < 8 ? w0  : w1,  gb2 + (k & 7), 64);
                u32x4 nv = *(const u32x4*)(h8i + (long)ik * DFEAT + q8 * 16);
                #pragma unroll
                for (int b = 0; b < 4; ++b) {
                    const unsigned u = nv[b];
                    acc[b * 4 + 0] += wk * (float)(signed char)(u & 0xFF);
                    acc[b * 4 + 1] += wk * (float)(signed char)((u >> 8) & 0xFF);
                    acc[b * 4 + 2] += wk * (float)(signed char)((u >> 16) & 0xFF);
                    acc[b * 4 + 3] += wk * (float)(signed char)(u >> 24);
                }
            }

            short8 ab0, ab1;
            #pragma unroll
            for (int d = 0; d < 8; ++d) { ab0[d] = f2bf(acc[d]); ab1[d] = f2bf(acc[8 + d]); }
            *(short8*)&xlds[i][((16 + 2 * q8)     ^ (i & 7)) * 8] = ab0;
            *(short8*)&xlds[i][((16 + 2 * q8 + 1) ^ (i & 7)) * 8] = ab1;
        }
    } else if constexpr (MODE == 1) {
        const int q  = l & 15;
        const int gb = l & 48;
        const int i0 = wvi * 16 + (l >> 4) * 4;
        #pragma unroll 1
        for (int r = 0; r < 4; ++r) {
            const int i = i0 + r;
            int n = nb + i; if (n >= N) n = N - 1;
            const int e0 = n * KNBR + q;
            int myidx = nbr32[idx64 ? 2 * e0 : e0];
            float myw = nbrw[e0];
            short8 hv = *(const short8*)(h16 + (long)n * DFEAT + q * 8);
            float acc[8] = {0.f,0.f,0.f,0.f,0.f,0.f,0.f,0.f};
            #pragma unroll
            for (int k = 0; k < KNBR; ++k) {
                int ik = __shfl(myidx, gb + k, 64);
                short8 nv = *(const short8*)(h16 + (long)ik * DFEAT + q * 8);
                float wk = __shfl(myw, gb + k, 64);
                #pragma unroll
                for (int d = 0; d < 8; ++d)
                    acc[d] += wk * bf2f((unsigned short)nv[d]);
            }
            *(short8*)&xlds[i][(q ^ (i & 7)) * 8] = hv;
            short8 ab;
            #pragma unroll
            for (int d = 0; d < 8; ++d) ab[d] = f2bf(acc[d]);
            *(short8*)&xlds[i][((16 + q) ^ (i & 7)) * 8] = ab;
        }
    } else {
        const int q  = l & 15;
        const int i0 = wvi * 16 + (l >> 4) * 4;
        #pragma unroll 1
        for (int r = 0; r < 4; ++r) {
            const int i = i0 + r;
            int n = nb + i; if (n >= N) n = N - 1;
            short8 hv;
            float acc[8] = {0.f,0.f,0.f,0.f,0.f,0.f,0.f,0.f};
            const f32x4* hrow = (const f32x4*)(h + (long)n * DFEAT + q * 8);
            f32x4 h0 = hrow[0], h1 = hrow[1];
            hv[0] = f2bf(h0[0]); hv[1] = f2bf(h0[1]); hv[2] = f2bf(h0[2]); hv[3] = f2bf(h0[3]);
            hv[4] = f2bf(h1[0]); hv[5] = f2bf(h1[1]); hv[6] = f2bf(h1[2]); hv[7] = f2bf(h1[3]);
            const int e0 = n * KNBR;
            #pragma unroll 4
            for (int k = 0; k < KNBR; ++k) {
                float w = nbrw[e0 + k];
                int idx = nbr32[idx64 ? 2 * (e0 + k) : (e0 + k)];
                const f32x4* nrow = (const f32x4*)(h + (long)idx * DFEAT + q * 8);
                f32x4 n0 = nrow[0], n1 = nrow[1];
                acc[0] += w * n0[0]; acc[1] += w * n0[1];
                acc[2] += w * n0[2]; acc[3] += w * n0[3];
                acc[4] += w * n1[0]; acc[5] += w * n1[1];
                acc[6] += w * n1[2]; acc[7] += w * n1[3];
            }
            *(short8*)&xlds[i][(q ^ (i & 7)) * 8] = hv;
            short8 ab;
            #pragma unroll
            for (int d = 0; d < 8; ++d) ab[d] = f2bf(acc[d]);
            *(short8*)&xlds[i][((16 + q) ^ (i & 7)) * 8] = ab;
        }
    }
    __syncthreads();

    // ---------------- Phase 2: MFMA GEMM (64 nodes x 128 j, K=256) ----------------
    const int wv  = wvi;          // wave owns j in [wv*32, wv*32+32)
    const int col = l & 15;
    const int kg  = l >> 4;       // 0..3

    f32x4 acc2[4][2];
    #pragma unroll
    for (int s = 0; s < 4; ++s)
        #pragma unroll
        for (int t = 0; t < 2; ++t)
            acc2[s][t] = (f32x4){0.f, 0.f, 0.f, 0.f};

    const unsigned short* wbase0 = wcat + (wv * 32 + col) * 256 + kg * 8;
    const unsigned short* wbase1 = wbase0 + 16 * 256;

    #pragma unroll
    for (int kk = 0; kk < 8; ++kk) {
        short8 b0 = *(const short8*)(wbase0 + kk * 32);   // B[k][col] = Wcat[j][k]
        short8 b1 = *(const short8*)(wbase1 + kk * 32);
        #pragma unroll
        for (int s = 0; s < 4; ++s) {
            const int row = s * 16 + col;                  // A row = node in tile
            const int c = (kk * 4 + kg) ^ (row & 7);       // swizzled 16B chunk
            short8 a = *(const short8*)&xlds[row][c * 8];
            acc2[s][0] = __builtin_amdgcn_mfma_f32_16x16x32_bf16(a, b0, acc2[s][0], 0, 0, 0);
            acc2[s][1] = __builtin_amdgcn_mfma_f32_16x16x32_bf16(a, b1, acc2[s][1], 0, 0, 0);
        }
    }

    // ---------------- Phase 3: GELU (exact erf) ----------------
    float y[4][2][4];
    #pragma unroll
    for (int s = 0; s < 4; ++s)
        #pragma unroll
        for (int t = 0; t < 2; ++t)
            #pragma unroll
            for (int r = 0; r < 4; ++r) {
                float x = acc2[s][t][r];
                y[s][t][r] = 0.5f * x * (1.0f + erff(x * 0.70710678118654752f));
            }

    __syncthreads();   // all xlds reads done before LN-scratch overlay writes

    // overlay LN scratch on the dead x tile
    float* lsum = (float*)&xlds[0][0];        // [4][64]
    float* lsq  = lsum + 4 * NPB;             // [4][64]

    // ---------------- Phase 4: LN stats ----------------
    #pragma unroll
    for (int s = 0; s < 4; ++s) {
        f32x4 sm, sq;
        #pragma unroll
        for (int r = 0; r < 4; ++r) {
            float a0 = y[s][0][r], a1 = y[s][1][r];
            sm[r] = a0 + a1;
            sq[r] = a0 * a0 + a1 * a1;
        }
        #pragma unroll
        for (int m = 1; m < 16; m <<= 1) {
            #pragma unroll
            for (int r = 0; r < 4; ++r) {
                sm[r] += __shfl_xor(sm[r], m, 64);
                sq[r] += __shfl_xor(sq[r], m, 64);
            }
        }
        if (col == 0) {
            *(f32x4*)&lsum[wv * NPB + s * 16 + kg * 4] = sm;
            *(f32x4*)&lsq [wv * NPB + s * 16 + kg * 4] = sq;
        }
    }
    __syncthreads();

    // ---------------- Phase 5: LN apply + store (non-temporal) ----------------
    const float g0  = gamma[wv * 32 + col];
    const float g1  = gamma[wv * 32 + 16 + col];
    const float be0 = beta [wv * 32 + col];
    const float be1 = beta [wv * 32 + 16 + col];

    #pragma unroll
    for (int s = 0; s < 4; ++s) {
        f32x4 sm = {0.f,0.f,0.f,0.f}, sq = {0.f,0.f,0.f,0.f};
        #pragma unroll
        for (int u = 0; u < 4; ++u) {
            f32x4 a = *(const f32x4*)&lsum[u * NPB + s * 16 + kg * 4];
            f32x4 b = *(const f32x4*)&lsq [u * NPB + s * 16 + kg * 4];
            sm += a; sq += b;
        }
        #pragma unroll
        for (int r = 0; r < 4; ++r) {
            const int i = s * 16 + kg * 4 + r;
            const int n = nb + i;
            if (n < N) {
                float mean = sm[r] * (1.0f / 128.0f);
                float var  = sq[r] * (1.0f / 128.0f) - mean * mean;
                float rstd = rsqrtf(var + 1e-5f);
                long o = (long)n * DFEAT + wv * 32 + col;
                __builtin_nontemporal_store((y[s][0][r] - mean) * rstd * g0 + be0, &out[o]);
                __builtin_nontemporal_store((y[s][1][r] - mean) * rstd * g1 + be1, &out[o + 16]);
            }
        }
    }
}

extern "C" void kernel_launch(void* const* d_in, const int* in_sizes, int n_in,
                              void* d_out, int out_size, void* d_ws, size_t ws_size,
                              hipStream_t stream) {
    const float* h     = (const float*)d_in[0];
    const int*   nbr   = (const int*)  d_in[1];
    const float* nbrw  = (const float*)d_in[2];
    const float* wself = (const float*)d_in[3];
    const float* wnei  = (const float*)d_in[4];
    const float* gamma = (const float*)d_in[5];
    const float* beta  = (const float*)d_in[6];
    const int N = in_sizes[0] / DFEAT;

    // layout: wcat 64K | h16 N*256 | sc N*4 | h8i N*128
    unsigned short* wcat = (unsigned short*)d_ws;
    unsigned short* h16  = (unsigned short*)((char*)d_ws + 65536);
    float*          sc   = (float*)((char*)d_ws + 65536 + (size_t)N * DFEAT * 2);
    unsigned char*  h8i  = (unsigned char*)((char*)sc + (size_t)N * 4);
    const size_t need16 = 65536 + (size_t)N * DFEAT * 2;
    const size_t need3  = need16 + (size_t)N * 4 + (size_t)N * DFEAT;

    const int blocks = (N + NPB - 1) / NPB;
    const int ntot8 = N * DFEAT / 8;
    const int pthreads = 4096 + ntot8;

    if (ws_size >= need3) {
        prep_kernel<<<(pthreads + 255) / 256, 256, 0, stream>>>(h, wself, wnei, h16, wcat, h8i, sc, ntot8);
        sage_fused_kernel<3><<<blocks, 256, 0, stream>>>(h, h16, h8i, sc, nbr, nbrw, wcat,
                                                         gamma, beta, (float*)d_out, N);
    } else if (ws_size >= need16) {
        prep_kernel<<<(pthreads + 255) / 256, 256, 0, stream>>>(h, wself, wnei, h16, wcat,
                                                                (unsigned char*)nullptr, (float*)nullptr, ntot8);
        sage_fused_kernel<1><<<blocks, 256, 0, stream>>>(h, h16, (const unsigned char*)nullptr,
                                                         (const float*)nullptr, nbr, nbrw, wcat,
                                                         gamma, beta, (float*)d_out, N);
    } else {
        prep_kernel<<<(4096 + 255) / 256, 256, 0, stream>>>(h, wself, wnei, h16, wcat,
                                                            (unsigned char*)nullptr, (float*)nullptr, 0);
        sage_fused_kernel<0><<<blocks, 256, 0, stream>>>(h, (const unsigned short*)nullptr,
                                                         (const unsigned char*)nullptr,
                                                         (const float*)nullptr, nbr, nbrw, wcat,
                                                         gamma, beta, (float*)d_out, N);
    }
}